// Round 13
// baseline (35.944 us; speedup 1.0000x reference)
//
#include <hip/hip_runtime.h>
#include <stdint.h>

#define N_IMG 16
#define H_DIM 512
#define W_DIM 512
#define PADR 15
#define BAND 8                  // output rows per mega block
#define HALO (BAND + 2 * PADR)  // 38 staged bitmap rows
#define WPR 18                  // 32-bit words per bitmap row: 1 pad + 16 data + 1 pad
#define NBANDS (H_DIM / BAND)   // 64
#define WROW (W_DIM / 32)       // 16 data words per row

// ws layout (poison-safe: every word written before read, every launch):
//   part @ 0      : 1024 blocks * 5 f32  [bce,in0,in1,un0,un1]
//   bm   @ 32 KiB : uint32 bm[N][512][16]  (bit c&31 of word c>>5 = target==1)
//
// Session ledger: fused finalize (R5/R10/R11) flips allocator to 32 VGPR ->
// dead. 512-thread mega never gets >64 VGPR (R1/R5/R8/R11) -> rich-per-thread
// designs spill at 512 thr. THIS round tests 256-thr blocks (budget should be
// 128 via launch_bounds(256,4)) with the 2-col/thread interior (R8 math,
// correctness-verified there). R7 fallback = 24.67 us.

// ---------------------------------------------------------------------------
// Stage 1: target -> bit-plane. int4 x2 per thread (8 elems), words assembled
// with 2 shfl_xor OR-merges. 2048 blocks x 256 threads; ~HBM-bound (16.8 MB).
// ---------------------------------------------------------------------------
__global__ __launch_bounds__(256) void bitmap_kernel(const int4* __restrict__ tg4,
                                                     uint32_t* __restrict__ bm) {
    const int tid = threadIdx.x;
    const size_t t = (size_t)blockIdx.x * 256 + tid;   // global thread, 8 ints each
    const int4 a = tg4[t * 2];
    const int4 b = tg4[t * 2 + 1];
    uint32_t by = (uint32_t)(a.x == 1) | ((uint32_t)(a.y == 1) << 1) |
                  ((uint32_t)(a.z == 1) << 2) | ((uint32_t)(a.w == 1) << 3) |
                  ((uint32_t)(b.x == 1) << 4) | ((uint32_t)(b.y == 1) << 5) |
                  ((uint32_t)(b.z == 1) << 6) | ((uint32_t)(b.w == 1) << 7);
    uint32_t w = by << (8 * (tid & 3));
    w |= __shfl_xor(w, 1);
    w |= __shfl_xor(w, 2);
    if ((tid & 3) == 0) bm[t >> 2] = w;
}

// ---------------------------------------------------------------------------
// Stage 2: fused 31x31 box-sum + loss. 256 threads x 2 adjacent cols x 8 rows
// (block tile 512x8 unchanged; grid 64x16). One ds_read2 + one 64-bit funnel
// yields BOTH columns' windows: v0=(dw>>s)&M31, v1=(dw>>(s+1))&M31 -> LDS
// reads halve, waves halve, 32 pred values in flight. ~90 live VGPRs; needs
// the 128-VGPR budget of launch_bounds(256,4) -- the hypothesis under test.
// ---------------------------------------------------------------------------
__global__ __launch_bounds__(256, 4) void mega_kernel(const uint32_t* __restrict__ bm,
                                                      const float* __restrict__ pred,
                                                      float* __restrict__ part) {
    __shared__ uint32_t B[HALO][WPR];
    const int tid = threadIdx.x;                 // col-pair index
    const int band = blockIdx.x;                 // 0..63
    const int n = blockIdx.y;
    const int r0 = band * BAND;
    const int c0 = tid * 2;

    // ---- bitmap halo staging: 608 words, <=3 per thread (issued together) ----
    const uint32_t* __restrict__ bmn = bm + (size_t)n * H_DIM * WROW;
    const int hrA = tid >> 4, wiA = tid & 15;    // words 0..255   (rows 0..15)
    const int hrB = hrA + 16;                    // words 256..511 (rows 16..31)
    const int hrC = hrA + 32;                    // words 512..607 (rows 32..37)
    const int raA = r0 - PADR + hrA;
    const int raB = r0 - PADR + hrB;
    const int raC = r0 - PADR + hrC;
    uint32_t wA = 0, wB = 0, wC = 0;
    if (raA >= 0 && raA < H_DIM) wA = bmn[raA * WROW + wiA];
    if (raB >= 0 && raB < H_DIM) wB = bmn[raB * WROW + wiA];
    if (tid < 96 && raC >= 0 && raC < H_DIM) wC = bmn[raC * WROW + wiA];

    // ---- pred float2 loads issued early (32 values outstanding) ----
    const size_t img = (size_t)n * H_DIM * W_DIM;
    const float* __restrict__ p0 = pred + img * 2 + (size_t)r0 * W_DIM + c0;
    const float* __restrict__ p1 = p0 + (size_t)H_DIM * W_DIM;
    float2 x0[BAND], x1[BAND];
#pragma unroll
    for (int rr = 0; rr < BAND; ++rr) {
        x0[rr] = *reinterpret_cast<const float2*>(p0 + rr * W_DIM);
        x1[rr] = *reinterpret_cast<const float2*>(p1 + rr * W_DIM);
    }

    // ---- LDS writes (wait only on bitmap loads; pred stays in flight) ----
    if (tid < 2 * HALO) B[tid >> 1][(tid & 1) ? (WPR - 1) : 0] = 0u;
    B[hrA][1 + wiA] = wA;
    B[hrB][1 + wiA] = wB;
    if (tid < 96) B[hrC][1 + wiA] = wC;
    __syncthreads();

    // ---- phase B: 38 rows, one funnel serves both columns ----
    const int b = c0 + (32 - PADR);              // window start bit of col c0
    const int q = b >> 5, s = b & 31;
    uint32_t run0 = 0, run1 = 0, mb0 = 0, mb1 = 0;
    uint32_t hlo0[7], hlo1[7], hhi0[7], hhi1[7];
#pragma unroll
    for (int i = 0; i < HALO; ++i) {
        const uint32_t lo = B[i][q];
        const uint32_t hi = B[i][q + 1];
        const uint64_t dw = ((uint64_t)hi << 32) | lo;
        const uint32_t v0 = (uint32_t)(dw >> s) & 0x7FFFFFFFu;
        const uint32_t v1 = (uint32_t)(dw >> (s + 1)) & 0x7FFFFFFFu;  // s+1<=32 ok
        const uint32_t h0 = (uint32_t)__popc(v0);
        const uint32_t h1 = (uint32_t)__popc(v1);
        if (i < 31) { run0 += h0; run1 += h1; }
        if (i < 7) { hlo0[i] = h0; hlo1[i] = h1; }
        if (i >= 31) { hhi0[i - 31] = h0; hhi1[i - 31] = h1; }
        if (i >= PADR && i < PADR + BAND) {      // center bits: col c0 -> v0 bit15
            mb0 |= ((v0 >> 15) & 1u) << (i - PADR);
            mb1 |= ((v0 >> 16) & 1u) << (i - PADR);
        }
    }

    // ---- register pin: pred + slide-h materialized HERE (R5-R7 discipline) ----
#pragma unroll
    for (int rr = 0; rr < BAND; ++rr)
        asm volatile("" : "+v"(x0[rr].x), "+v"(x0[rr].y), "+v"(x1[rr].x), "+v"(x1[rr].y));
#pragma unroll
    for (int i = 0; i < 7; ++i)
        asm volatile("" : "+v"(hlo0[i]), "+v"(hlo1[i]), "+v"(hhi0[i]), "+v"(hhi1[i]));

    // ---- loss math: 8 rows x 2 cols x 2 channels ----
    const float cw0 = (float)(min(c0 + PADR, W_DIM - 1) - max(c0 - PADR, 0) + 1);
    const float cw1 = (float)(min(c0 + 1 + PADR, W_DIM - 1) - max(c0 + 1 - PADR, 0) + 1);
    const float inv961 = 1.0f / 961.0f;
    float bce = 0.f, in0 = 0.f, in1 = 0.f, un0 = 0.f, un1 = 0.f;

    auto docol = [&](float xc0, float xc1, uint32_t V, uint32_t mbit, float cnt) {
        const float m1 = (float)mbit;
        const float m0 = 1.0f - m1;
        const float box1 = (float)V * inv961;
        const float box0 = (cnt - (float)V) * inv961;
        const float w1f = 1.0f + 5.0f * fabsf(box1 - m1);
        const float w0f = 1.0f + 5.0f * fabsf(box0 - m0);
        {   // channel 0
            const float x = xc0;
            const float t = __expf(-fabsf(x));
            const float inv = __builtin_amdgcn_rcpf(1.0f + t);   // v_rcp_f32
            const float p = (x >= 0.f) ? inv : t * inv;
            bce += fmaxf(x, 0.f) - x * m0 + __logf(1.0f + t);
            in0 += p * m0 * w0f;
            un0 += (p + m0) * w0f;
        }
        {   // channel 1
            const float x = xc1;
            const float t = __expf(-fabsf(x));
            const float inv = __builtin_amdgcn_rcpf(1.0f + t);
            const float p = (x >= 0.f) ? inv : t * inv;
            bce += fmaxf(x, 0.f) - x * m1 + __logf(1.0f + t);
            in1 += p * m1 * w1f;
            un1 += (p + m1) * w1f;
        }
    };

#pragma unroll
    for (int rr = 0; rr < BAND; ++rr) {
        const int r = r0 + rr;
        const float cnth = (float)(min(r + PADR, H_DIM - 1) - max(r - PADR, 0) + 1);
        docol(x0[rr].x, x1[rr].x, run0, (mb0 >> rr) & 1u, cnth * cw0);
        docol(x0[rr].y, x1[rr].y, run1, (mb1 >> rr) & 1u, cnth * cw1);
        if (rr < BAND - 1) {                     // slide vertical window
            run0 += hhi0[rr] - hlo0[rr];
            run1 += hhi1[rr] - hlo1[rr];
        }
    }

    // ---- block reduction: 4 waves x 5 values -> private part slot ----
    __shared__ float red[4 * 5];
    const int lane = tid & 63, wv = tid >> 6;
    float v[5] = {bce, in0, in1, un0, un1};
#pragma unroll
    for (int k = 0; k < 5; ++k)
#pragma unroll
        for (int off = 32; off > 0; off >>= 1)
            v[k] += __shfl_down(v[k], off);
    if (lane == 0)
#pragma unroll
        for (int k = 0; k < 5; ++k) red[wv * 5 + k] = v[k];
    __syncthreads();
    if (tid == 0) {
        float s2[5];
#pragma unroll
        for (int k = 0; k < 5; ++k) {
            s2[k] = red[k];
            for (int w2 = 1; w2 < 4; ++w2) s2[k] += red[w2 * 5 + k];
        }
        float* p = part + (size_t)(n * NBANDS + band) * 5;
#pragma unroll
        for (int k = 0; k < 5; ++k) p[k] = s2[k];
    }
}

// ---------------------------------------------------------------------------
// Finalize: reduce 1024 block-partials -> out[0]. One block.
// 16 threads per image; each accumulates 4 partial rows.
// ---------------------------------------------------------------------------
__global__ __launch_bounds__(256) void finalize_kernel(const float* __restrict__ part,
                                                       float* __restrict__ out) {
    const int tid = threadIdx.x;   // 0..255
    const int n = tid >> 4;        // image
    const int i = tid & 15;
    float bce = 0.f, in0 = 0.f, in1 = 0.f, un0 = 0.f, un1 = 0.f;
#pragma unroll
    for (int j = 0; j < 4; ++j) {
        const float* p = part + (size_t)(n * NBANDS + j * 16 + i) * 5;
        bce += p[0]; in0 += p[1]; in1 += p[2]; un0 += p[3]; un1 += p[4];
    }
#pragma unroll
    for (int off = 8; off > 0; off >>= 1) {
        bce += __shfl_xor(bce, off, 16);
        in0 += __shfl_xor(in0, off, 16);
        in1 += __shfl_xor(in1, off, 16);
        un0 += __shfl_xor(un0, off, 16);
        un1 += __shfl_xor(un1, off, 16);
    }
    __shared__ float fb[16], fw[16];
    if (i == 0) {
        fb[n] = bce;
        fw[n] = (1.0f - (in0 + 1.0f) / (un0 - in0 + 1.0f)) +
                (1.0f - (in1 + 1.0f) / (un1 - in1 + 1.0f));
    }
    __syncthreads();
    if (tid == 0) {
        float sb = 0.f, sw = 0.f;
#pragma unroll
        for (int k = 0; k < 16; ++k) { sb += fb[k]; sw += fw[k]; }
        out[0] = sb / 8388608.0f + sw * (1.0f / 32.0f);  // 16*2*512*512 ; 32 (n,c) pairs
    }
}

extern "C" void kernel_launch(void* const* d_in, const int* in_sizes, int n_in,
                              void* d_out, int out_size, void* d_ws, size_t ws_size,
                              hipStream_t stream) {
    const float* pred = (const float*)d_in[0];
    const int* target = (const int*)d_in[1];
    float* part = (float*)d_ws;
    uint32_t* bm = (uint32_t*)((char*)d_ws + 32768);

    bitmap_kernel<<<2048, 256, 0, stream>>>((const int4*)target, bm);
    dim3 grid(NBANDS, N_IMG);
    mega_kernel<<<grid, 256, 0, stream>>>(bm, pred, part);
    finalize_kernel<<<1, 256, 0, stream>>>(part, (float*)d_out);
}

// Round 14
// 24.944 us; speedup vs baseline: 1.4410x; 1.4410x over previous
//
#include <hip/hip_runtime.h>
#include <stdint.h>

#define N_IMG 16
#define H_DIM 512
#define W_DIM 512
#define PADR 15
#define BAND 8                  // output rows per mega block
#define HALO (BAND + 2 * PADR)  // 38 staged bitmap rows
#define WPR 18                  // 32-bit words per bitmap row: 1 pad + 16 data + 1 pad
#define NBANDS (H_DIM / BAND)   // 64
#define WROW (W_DIM / 32)       // 16 data words per row

// ws layout (poison-safe: every word written before read, every launch):
//   part @ 0      : 1024 blocks * 5 f32  [bce,in0,in1,un0,un1]
//   bm   @ 32 KiB : uint32 bm[N][512][16]  (bit c&31 of word c>>5 = target==1)
//
// FINAL (session converged). Ledger of falsified alternatives — do not retry:
//  - fused last-block finalize (R5/R11): allocator tail-flips to 32 VGPR,
//    pred loads serialize -> ~2x slower. Unfixable from source (pins tested).
//  - 2-col/thread (R8 @512thr, R13 @256thr): needs >64 live VGPRs (spill) or
//    halves occupancy (latency exposed). 46.8 / 35.9 us.
//  - separable pre-pass images (R9 bytes, R10 packed dwords): 35.5 / 28.9 us.
// Optimum = 64 VGPR x 32 waves/CU x pinned batched loads. 24.67-24.74 us (x2).

// ---------------------------------------------------------------------------
// Stage 1: target -> bit-plane. int4 x2 per thread (8 elems), words assembled
// with 2 shfl_xor OR-merges. 2048 blocks x 256 threads; ~HBM-bound (16.8 MB).
// ---------------------------------------------------------------------------
__global__ __launch_bounds__(256) void bitmap_kernel(const int4* __restrict__ tg4,
                                                     uint32_t* __restrict__ bm) {
    const int tid = threadIdx.x;
    const size_t t = (size_t)blockIdx.x * 256 + tid;   // global thread, 8 ints each
    const int4 a = tg4[t * 2];
    const int4 b = tg4[t * 2 + 1];
    uint32_t by = (uint32_t)(a.x == 1) | ((uint32_t)(a.y == 1) << 1) |
                  ((uint32_t)(a.z == 1) << 2) | ((uint32_t)(a.w == 1) << 3) |
                  ((uint32_t)(b.x == 1) << 4) | ((uint32_t)(b.y == 1) << 5) |
                  ((uint32_t)(b.z == 1) << 6) | ((uint32_t)(b.w == 1) << 7);
    uint32_t w = by << (8 * (tid & 3));
    w |= __shfl_xor(w, 1);
    w |= __shfl_xor(w, 2);
    if ((tid & 3) == 0) bm[t >> 2] = w;
}

// ---------------------------------------------------------------------------
// Stage 2: fused 31x31 box-sum (popcount over bit-plane) + elementwise loss.
// Block = 512 threads (one per col) x 8 output rows. 1024 blocks -> 4/CU.
// All 38 horizontal window popcounts computed ONCE in the init loop; the 14
// needed by the vertical slide are register-pinned (pins stop the allocator
// from sinking/recomputing loads). Sigmoid via v_rcp (no div sequence).
// ---------------------------------------------------------------------------
__global__ __launch_bounds__(512, 8) void mega_kernel(const uint32_t* __restrict__ bm,
                                                      const float* __restrict__ pred,
                                                      float* __restrict__ part) {
    __shared__ uint32_t B[HALO][WPR];
    const int tid = threadIdx.x;                 // = col
    const int band = blockIdx.x;                 // 0..63
    const int n = blockIdx.y;
    const int r0 = band * BAND;
    const int col = tid;

    // ---- bitmap halo staging: 38 rows x 16 words = 608 loads, 2 per thread ----
    const uint32_t* __restrict__ bmn = bm + (size_t)n * H_DIM * WROW;
    const int hr0 = tid >> 4, wi = tid & 15;     // task 0: t = tid
    const int ra = r0 - PADR + hr0;
    uint32_t w0 = 0, w1 = 0;
    if (ra >= 0 && ra < H_DIM) w0 = bmn[ra * WROW + wi];
    const int hr1 = hr0 + 32;                    // task 1: t = tid + 512 (tid < 96)
    const int rb = r0 - PADR + hr1;
    if (tid < 96 && rb >= 0 && rb < H_DIM) w1 = bmn[rb * WROW + wi];

    // ---- pred loads issued early: outstanding across staging+barrier+popcounts
    const size_t img = (size_t)n * H_DIM * W_DIM;
    const float* __restrict__ p0 = pred + img * 2 + (size_t)r0 * W_DIM + col;
    const float* __restrict__ p1 = p0 + (size_t)H_DIM * W_DIM;
    float x0[BAND], x1[BAND];
#pragma unroll
    for (int rr = 0; rr < BAND; ++rr) {
        x0[rr] = p0[rr * W_DIM];
        x1[rr] = p1[rr * W_DIM];
    }

    // ---- LDS writes (wait only on bitmap loads; pred stays in flight) ----
    if (tid < 2 * HALO) B[tid >> 1][(tid & 1) ? (WPR - 1) : 0] = 0u;
    B[hr0][1 + wi] = w0;
    if (tid < 96) B[hr1][1 + wi] = w1;
    __syncthreads();

    // ---- phase B: ALL 38 horizontal 31-bit window popcounts, one pass ----
    const int b = col + (32 - PADR);             // window start bit (word 0 = pad)
    const int q = b >> 5, s = b & 31;
    uint32_t run = 0, mbits = 0;
    uint32_t hlo[7], hhi[7];                     // h[0..6], h[31..37] for the slide
#pragma unroll
    for (int i = 0; i < HALO; ++i) {
        const uint32_t lo = B[i][q];
        const uint32_t hi = B[i][q + 1];
        const uint32_t val =
            (uint32_t)((((uint64_t)hi << 32) | lo) >> s) & 0x7FFFFFFFu;  // v_alignbit
        const uint32_t hv = (uint32_t)__popc(val);
        if (i < 31) run += hv;                   // initial vertical window
        if (i < 7) hlo[i] = hv;
        if (i >= 31) hhi[i - 31] = hv;
        if (i >= PADR && i < PADR + BAND)
            mbits |= ((val >> PADR) & 1u) << (i - PADR);  // center bit = window bit 15
    }

    // ---- register pin: x0/x1 and slide h-values must be materialized HERE
#pragma unroll
    for (int rr = 0; rr < BAND; ++rr) asm volatile("" : "+v"(x0[rr]), "+v"(x1[rr]));
#pragma unroll
    for (int i = 0; i < 7; ++i) asm volatile("" : "+v"(hlo[i]), "+v"(hhi[i]));

    // ---- loss math ----
    const int cntw = min(col + PADR, W_DIM - 1) - max(col - PADR, 0) + 1;
    const float inv961 = 1.0f / 961.0f;
    float bce = 0.f, in0 = 0.f, in1 = 0.f, un0 = 0.f, un1 = 0.f;

#pragma unroll
    for (int rr = 0; rr < BAND; ++rr) {
        const int r = r0 + rr;
        const int cnth = min(r + PADR, H_DIM - 1) - max(r - PADR, 0) + 1;
        const float cnt = (float)(cnth * cntw);
        const float m1 = (float)((mbits >> rr) & 1u);
        const float m0 = 1.0f - m1;
        const float V = (float)run;
        const float box1 = V * inv961;
        const float box0 = (cnt - V) * inv961;
        const float w1f = 1.0f + 5.0f * fabsf(box1 - m1);
        const float w0f = 1.0f + 5.0f * fabsf(box0 - m0);
        {   // channel 0
            const float x = x0[rr];
            const float t = __expf(-fabsf(x));
            const float inv = __builtin_amdgcn_rcpf(1.0f + t);   // v_rcp_f32
            const float p = (x >= 0.f) ? inv : t * inv;
            bce += fmaxf(x, 0.f) - x * m0 + __logf(1.0f + t);
            in0 += p * m0 * w0f;
            un0 += (p + m0) * w0f;
        }
        {   // channel 1
            const float x = x1[rr];
            const float t = __expf(-fabsf(x));
            const float inv = __builtin_amdgcn_rcpf(1.0f + t);
            const float p = (x >= 0.f) ? inv : t * inv;
            bce += fmaxf(x, 0.f) - x * m1 + __logf(1.0f + t);
            in1 += p * m1 * w1f;
            un1 += (p + m1) * w1f;
        }
        if (rr < BAND - 1)   // slide vertical window: 2 int ops, no LDS
            run += hhi[rr] - hlo[rr];
    }

    // ---- block reduction: 5 values -> plain store to private slot ----
    __shared__ float red[8 * 5];
    const int lane = tid & 63, wv = tid >> 6;
    float v[5] = {bce, in0, in1, un0, un1};
#pragma unroll
    for (int k = 0; k < 5; ++k)
#pragma unroll
        for (int off = 32; off > 0; off >>= 1)
            v[k] += __shfl_down(v[k], off);
    if (lane == 0)
#pragma unroll
        for (int k = 0; k < 5; ++k) red[wv * 5 + k] = v[k];
    __syncthreads();
    if (tid == 0) {
        float s2[5];
#pragma unroll
        for (int k = 0; k < 5; ++k) {
            s2[k] = red[k];
            for (int w2 = 1; w2 < 8; ++w2) s2[k] += red[w2 * 5 + k];
        }
        float* p = part + (size_t)(n * NBANDS + band) * 5;
#pragma unroll
        for (int k = 0; k < 5; ++k) p[k] = s2[k];
    }
}

// ---------------------------------------------------------------------------
// Finalize: reduce 1024 block-partials -> out[0]. One block.
// 16 threads per image; each accumulates 4 partial rows.
// ---------------------------------------------------------------------------
__global__ __launch_bounds__(256) void finalize_kernel(const float* __restrict__ part,
                                                       float* __restrict__ out) {
    const int tid = threadIdx.x;   // 0..255
    const int n = tid >> 4;        // image
    const int i = tid & 15;
    float bce = 0.f, in0 = 0.f, in1 = 0.f, un0 = 0.f, un1 = 0.f;
#pragma unroll
    for (int j = 0; j < 4; ++j) {
        const float* p = part + (size_t)(n * NBANDS + j * 16 + i) * 5;
        bce += p[0]; in0 += p[1]; in1 += p[2]; un0 += p[3]; un1 += p[4];
    }
#pragma unroll
    for (int off = 8; off > 0; off >>= 1) {
        bce += __shfl_xor(bce, off, 16);
        in0 += __shfl_xor(in0, off, 16);
        in1 += __shfl_xor(in1, off, 16);
        un0 += __shfl_xor(un0, off, 16);
        un1 += __shfl_xor(un1, off, 16);
    }
    __shared__ float fb[16], fw[16];
    if (i == 0) {
        fb[n] = bce;
        fw[n] = (1.0f - (in0 + 1.0f) / (un0 - in0 + 1.0f)) +
                (1.0f - (in1 + 1.0f) / (un1 - in1 + 1.0f));
    }
    __syncthreads();
    if (tid == 0) {
        float sb = 0.f, sw = 0.f;
#pragma unroll
        for (int k = 0; k < 16; ++k) { sb += fb[k]; sw += fw[k]; }
        out[0] = sb / 8388608.0f + sw * (1.0f / 32.0f);  // 16*2*512*512 ; 32 (n,c) pairs
    }
}

extern "C" void kernel_launch(void* const* d_in, const int* in_sizes, int n_in,
                              void* d_out, int out_size, void* d_ws, size_t ws_size,
                              hipStream_t stream) {
    const float* pred = (const float*)d_in[0];
    const int* target = (const int*)d_in[1];
    float* part = (float*)d_ws;
    uint32_t* bm = (uint32_t*)((char*)d_ws + 32768);

    bitmap_kernel<<<2048, 256, 0, stream>>>((const int4*)target, bm);
    dim3 grid(NBANDS, N_IMG);
    mega_kernel<<<grid, 512, 0, stream>>>(bm, pred, part);
    finalize_kernel<<<1, 256, 0, stream>>>(part, (float*)d_out);
}